// Round 7
// baseline (326.022 us; speedup 1.0000x reference)
//
#include <hip/hip_runtime.h>

#define NPATH  2048
#define DIM    64
#define NSTEPS 500
#define PPW    16   // paths per wave; one wave (64-thread block) per 16 paths

typedef __attribute__((ext_vector_type(8))) short bf16x8;
typedef __attribute__((ext_vector_type(4))) float f32x4;

union FragU { bf16x8 v; unsigned int u[4]; };

__device__ __forceinline__ unsigned int pk_bf16(float lo, float hi) {
    unsigned int r;
    asm("v_cvt_pk_bf16_f32 %0, %1, %2" : "=v"(r) : "v"(lo), "v"(hi));
    return r;
}

// One wave per 16 paths. Per step: 16x mfma_f32_16x16x32_bf16 computes both
// 64x64 matvecs for 16 paths (bias pre-loaded into the accumulator).
// Matrices live in LDS in fragment-linear layout (conflict-free ds_read_b128,
// re-read each step -> no register-residency fight with the allocator).
// State stays f32 in C-layout regs; the step recurrence goes through a
// 4KB XOR-swizzled LDS tile (C-layout writes -> A-fragment reads).
// A and B fragments are packed with the SAME k-order, so any internal HW
// k-permutation cancels in the contraction. No block barriers (single wave).
__attribute__((amdgpu_waves_per_eu(1, 1)))
__global__ __launch_bounds__(64) void sde_mfma_kernel(
    const float* __restrict__ x0,
    const float* __restrict__ dW,
    const float* __restrict__ drift,
    const float* __restrict__ drift_bias,
    const float* __restrict__ diffusion,
    const float* __restrict__ diffusion_bias,
    const float* __restrict__ ts,
    float* __restrict__ out)
{
    __shared__ float  xt[PPW * DIM];     // x tile [path][dim] f32, XOR-swizzled
    __shared__ uint4  bfr[16][64];       // B-frags: [mat*8+n*2+kk][lane], linear
    __shared__ float2 dtp[NSTEPS + 1];   // {dt, sqrt(dt)}

    const int lane  = threadIdx.x;       // 0..63
    const int c     = lane & 15;
    const int h     = lane >> 4;
    const int pbase = blockIdx.x * PPW;

    // (dt, sqrt(dt)) table — dt = ts[i+1]-ts[i] in f32, matching reference
    for (int i = lane; i < NSTEPS; i += 64) {
        const float d = ts[i + 1] - ts[i];
        dtp[i] = make_float2(d, sqrtf(d));
    }

    // ---- B-fragments (both matrices), built once, stored fragment-linear ----
    // out[p][d] = sum_k x[p][k] * M[d][k]  =>  B[k][col=d] = M[d][k];
    // frag (mat,n,kk): lane holds M[16n+c][32kk+8h+e], e=0..7 (contiguous!)
#pragma unroll
    for (int mat = 0; mat < 2; ++mat) {
        const float* __restrict__ M = mat ? diffusion : drift;
#pragma unroll
        for (int n = 0; n < 4; ++n) {
#pragma unroll
            for (int kk = 0; kk < 2; ++kk) {
                const int row = 16 * n + c;
                const int col = 32 * kk + 8 * h;
                const float4 lo = *(const float4*)(M + row * DIM + col);
                const float4 hi = *(const float4*)(M + row * DIM + col + 4);
                uint4 u;
                u.x = pk_bf16(lo.x, lo.y); u.y = pk_bf16(lo.z, lo.w);
                u.z = pk_bf16(hi.x, hi.y); u.w = pk_bf16(hi.z, hi.w);
                bfr[mat * 8 + n * 2 + kk][lane] = u;
            }
        }
    }

    // biases per output dim (C/D col = lane&15)
    float bdr[4], bdi[4];
#pragma unroll
    for (int n = 0; n < 4; ++n) {
        bdr[n] = drift_bias[16 * n + c];
        bdi[n] = diffusion_bias[16 * n + c];
    }

    // ---- state init (C layout: value (j,n) = path 4h+j, dim c+16n) ----
    const float* dwp[4];
    float* outp[4];
    float xst[16];
#pragma unroll
    for (int j = 0; j < 4; ++j) {
        const int p = pbase + 4 * h + j;
        dwp[j]  = dW  + (size_t)p * NSTEPS * DIM + c;
        outp[j] = out + (size_t)p * (NSTEPS + 1) * DIM + c;
#pragma unroll
        for (int n = 0; n < 4; ++n) {
            const float v = x0[p * DIM + c + 16 * n];
            xst[j * 4 + n] = v;
            __builtin_nontemporal_store(v, outp[j] + 16 * n);  // ys[:,0,:]
            xt[(4 * h + j) * DIM + ((c + 16 * n) ^ (((4 * h + j) & 7) << 2))] = v;
        }
    }

    // dW ring, depth 2 (consume-then-prefetch; static indices only)
    float rA[16], rB[16];
#pragma unroll
    for (int j = 0; j < 4; ++j)
#pragma unroll
        for (int n = 0; n < 4; ++n) {
            rA[j * 4 + n] = dwp[j][0 * DIM + 16 * n];
            rB[j * 4 + n] = dwp[j][1 * DIM + 16 * n];
        }

    __syncthreads();   // single wave: just orders LDS init before the loop

#define STEP(S, R, PF)                                                        \
    {                                                                         \
        const float2 dtc = dtp[S];                                            \
        /* A-frags from x tile: row = c (path), dims 32kk+8h+0..7 */          \
        FragU a0, a1;                                                         \
        {                                                                     \
            const int swz = (c & 7) << 2;                                     \
            const float* xr = &xt[c * DIM];                                   \
            const float4 l0 = *(const float4*)&xr[(8 * h + 0) ^ swz];         \
            const float4 h0 = *(const float4*)&xr[(8 * h + 4) ^ swz];         \
            const float4 l1 = *(const float4*)&xr[(32 + 8 * h + 0) ^ swz];    \
            const float4 h1 = *(const float4*)&xr[(32 + 8 * h + 4) ^ swz];    \
            a0.u[0] = pk_bf16(l0.x, l0.y); a0.u[1] = pk_bf16(l0.z, l0.w);     \
            a0.u[2] = pk_bf16(h0.x, h0.y); a0.u[3] = pk_bf16(h0.z, h0.w);     \
            a1.u[0] = pk_bf16(l1.x, l1.y); a1.u[1] = pk_bf16(l1.z, l1.w);     \
            a1.u[2] = pk_bf16(h1.x, h1.y); a1.u[3] = pk_bf16(h1.z, h1.w);     \
        }                                                                     \
        __builtin_amdgcn_wave_barrier();                                      \
        _Pragma("unroll")                                                     \
        for (int n = 0; n < 4; ++n) {                                         \
            const uint4 t0 = bfr[0 * 8 + n * 2 + 0][lane];                    \
            const uint4 t1 = bfr[0 * 8 + n * 2 + 1][lane];                    \
            const uint4 t2 = bfr[1 * 8 + n * 2 + 0][lane];                    \
            const uint4 t3 = bfr[1 * 8 + n * 2 + 1][lane];                    \
            FragU bd0, bd1, bs0, bs1;                                         \
            bd0.u[0] = t0.x; bd0.u[1] = t0.y; bd0.u[2] = t0.z; bd0.u[3] = t0.w; \
            bd1.u[0] = t1.x; bd1.u[1] = t1.y; bd1.u[2] = t1.z; bd1.u[3] = t1.w; \
            bs0.u[0] = t2.x; bs0.u[1] = t2.y; bs0.u[2] = t2.z; bs0.u[3] = t2.w; \
            bs1.u[0] = t3.x; bs1.u[1] = t3.y; bs1.u[2] = t3.z; bs1.u[3] = t3.w; \
            f32x4 adr = {bdr[n], bdr[n], bdr[n], bdr[n]};                     \
            f32x4 adi = {bdi[n], bdi[n], bdi[n], bdi[n]};                     \
            adr = __builtin_amdgcn_mfma_f32_16x16x32_bf16(a0.v, bd0.v, adr, 0, 0, 0); \
            adr = __builtin_amdgcn_mfma_f32_16x16x32_bf16(a1.v, bd1.v, adr, 0, 0, 0); \
            adi = __builtin_amdgcn_mfma_f32_16x16x32_bf16(a0.v, bs0.v, adi, 0, 0, 0); \
            adi = __builtin_amdgcn_mfma_f32_16x16x32_bf16(a1.v, bs1.v, adi, 0, 0, 0); \
            _Pragma("unroll")                                                 \
            for (int j = 0; j < 4; ++j) {                                     \
                const float xn = fmaf(dtc.x, adr[j], xst[j * 4 + n])          \
                                 + adi[j] * (dtc.y * R[j * 4 + n]);           \
                xst[j * 4 + n] = xn;                                          \
                __builtin_nontemporal_store(                                  \
                    xn, outp[j] + (size_t)((S) + 1) * DIM + 16 * n);          \
                xt[(4 * h + j) * DIM +                                        \
                   ((c + 16 * n) ^ (((4 * h + j) & 7) << 2))] = xn;           \
            }                                                                 \
        }                                                                     \
        if (PF) {                                                             \
            _Pragma("unroll")                                                 \
            for (int j = 0; j < 4; ++j)                                       \
                _Pragma("unroll")                                             \
                for (int n = 0; n < 4; ++n)                                   \
                    R[j * 4 + n] = dwp[j][(size_t)((S) + 2) * DIM + 16 * n];  \
        }                                                                     \
        __builtin_amdgcn_wave_barrier();                                      \
    }

    // steps 0..497 with depth-2 prefetch (issued after consumption)
    for (int it = 0; it < NSTEPS / 2 - 1; ++it) {
        const int s = it * 2;
        STEP(s + 0, rA, 1)
        STEP(s + 1, rB, 1)
    }
    // steps 498, 499: no prefetch
    STEP(NSTEPS - 2, rA, 0)
    STEP(NSTEPS - 1, rB, 0)
#undef STEP
}

extern "C" void kernel_launch(void* const* d_in, const int* in_sizes, int n_in,
                              void* d_out, int out_size, void* d_ws, size_t ws_size,
                              hipStream_t stream) {
    const float* x0             = (const float*)d_in[0];
    const float* dW             = (const float*)d_in[1];
    const float* drift          = (const float*)d_in[2];
    const float* drift_bias     = (const float*)d_in[3];
    const float* diffusion      = (const float*)d_in[4];
    const float* diffusion_bias = (const float*)d_in[5];
    const float* ts             = (const float*)d_in[6];
    float* out = (float*)d_out;

    dim3 grid(NPATH / PPW);   // 128 blocks
    dim3 block(64);           // one wave
    hipLaunchKernelGGL(sde_mfma_kernel, grid, block, 0, stream,
                       x0, dW, drift, drift_bias, diffusion, diffusion_bias,
                       ts, out);
}

// Round 8
// 150.970 us; speedup vs baseline: 2.1595x; 2.1595x over previous
//
#include <hip/hip_runtime.h>

#define NPATH  2048
#define DIM    64
#define NSTEPS 500
#define PPW    16   // paths per tile (one block per tile, 4 waves)

typedef __attribute__((ext_vector_type(8))) short bf16x8;
typedef __attribute__((ext_vector_type(4))) float f32x4;

union FragU { bf16x8 v; unsigned int u[4]; uint4 q; };

__device__ __forceinline__ unsigned int pk_bf16(float lo, float hi) {
    unsigned int r;
    asm("v_cvt_pk_bf16_f32 %0, %1, %2" : "=v"(r) : "v"(lo), "v"(hi));
    return r;
}

// One block = one 16-path tile, 4 waves; wave n owns output-dim quarter
// 16n..16n+15. B-frags (its quarter of A and C, bf16) live in 16 VGPRs,
// built once. State tile xt is bf16 in LDS, ping-pong buffered, XOR-swizzled
// ((dim>>1) ^ ((path&7)<<2) on dwords): reads are 2 raw ds_read_b128 (no
// cvt), writes 4 cvt+ds_write_b16. One RAW barrier per step (lgkmcnt-only
// drain) so the depth-4 dW prefetch ring is never vmcnt(0)-drained.
// NO asm reg pins anywhere (r3-r6 lesson: pins poison the allocator).
__attribute__((amdgpu_waves_per_eu(1, 4)))
__global__ __launch_bounds__(256) void sde_mfma_mw_kernel(
    const float* __restrict__ x0,
    const float* __restrict__ dW,
    const float* __restrict__ drift,
    const float* __restrict__ drift_bias,
    const float* __restrict__ diffusion,
    const float* __restrict__ diffusion_bias,
    const float* __restrict__ ts,
    float* __restrict__ out)
{
    __shared__ __align__(16) unsigned short xt[2][PPW * DIM];  // bf16, swizzled
    __shared__ float2 dtp[NSTEPS];

    const int tid   = threadIdx.x;
    const int wn    = tid >> 6;          // wave = output-dim quarter
    const int lane  = tid & 63;
    const int c     = lane & 15;
    const int h     = lane >> 4;
    const int pbase = blockIdx.x * PPW;
    const int mydim = 16 * wn + c;

    // (dt, sqrt(dt)) table — dt = ts[i+1]-ts[i] in f32, matching reference
    for (int i = tid; i < NSTEPS; i += 256) {
        const float d = ts[i + 1] - ts[i];
        dtp[i] = make_float2(d, sqrtf(d));
    }

    // B-frags for this wave's quarter (r7-verified k-packing: lane (c,h)
    // holds M[mydim][32*kk + 8*h + e], e=0..7, matching the A-side packing)
    FragU bd0, bd1, bs0, bs1;
    {
        const float* Ar = drift     + mydim * DIM + 8 * h;
        const float* Cr = diffusion + mydim * DIM + 8 * h;
        float4 t;
        t = *(const float4*)(Ar +  0); bd0.u[0] = pk_bf16(t.x, t.y); bd0.u[1] = pk_bf16(t.z, t.w);
        t = *(const float4*)(Ar +  4); bd0.u[2] = pk_bf16(t.x, t.y); bd0.u[3] = pk_bf16(t.z, t.w);
        t = *(const float4*)(Ar + 32); bd1.u[0] = pk_bf16(t.x, t.y); bd1.u[1] = pk_bf16(t.z, t.w);
        t = *(const float4*)(Ar + 36); bd1.u[2] = pk_bf16(t.x, t.y); bd1.u[3] = pk_bf16(t.z, t.w);
        t = *(const float4*)(Cr +  0); bs0.u[0] = pk_bf16(t.x, t.y); bs0.u[1] = pk_bf16(t.z, t.w);
        t = *(const float4*)(Cr +  4); bs0.u[2] = pk_bf16(t.x, t.y); bs0.u[3] = pk_bf16(t.z, t.w);
        t = *(const float4*)(Cr + 32); bs1.u[0] = pk_bf16(t.x, t.y); bs1.u[1] = pk_bf16(t.z, t.w);
        t = *(const float4*)(Cr + 36); bs1.u[2] = pk_bf16(t.x, t.y); bs1.u[3] = pk_bf16(t.z, t.w);
    }
    const float bdr = drift_bias[mydim];
    const float bdi = diffusion_bias[mydim];

    // state (4 paths x this lane's dim), pointers, precomputed xt offsets
    float xst[4];
    const float* dwq[4];
    float* op[4];
    unsigned int woff[4];                 // halfword index for xt writes
#pragma unroll
    for (int j = 0; j < 4; ++j) {
        const int pp = 4 * h + j;
        const int p  = pbase + pp;
        dwq[j] = dW  + (size_t)p * NSTEPS * DIM + mydim;
        op[j]  = out + (size_t)p * (NSTEPS + 1) * DIM + mydim;
        woff[j] = (unsigned)((pp * 32 + ((mydim >> 1) ^ ((pp & 7) << 2))) * 2 + (c & 1));
        const float v = x0[p * DIM + mydim];
        xst[j] = v;
        __builtin_nontemporal_store(v, op[j]);          // ys[:,0,:]
        xt[0][woff[j]] = (unsigned short)pk_bf16(v, v); // x tile for step 0
    }

    // step-invariant read offsets (uint4 granularity; swizzle folded in)
    const int ra0 = c * 8 + (h ^ (c & 7));          // dims 8h+0..7   of path c
    const int ra1 = c * 8 + ((4 + h) ^ (c & 7));    // dims 32+8h+0..7
    const uint4* xr0 = (const uint4*)xt[0];
    const uint4* xr1 = (const uint4*)xt[1];
    unsigned short* xw0 = xt[0];
    unsigned short* xw1 = xt[1];

    // dW prefetch ring, depth 4 (named rings, static indices only)
    float R0[4], R1[4], R2[4], R3[4];
#pragma unroll
    for (int j = 0; j < 4; ++j) {
        R0[j] = dwq[j][0 * DIM];
        R1[j] = dwq[j][1 * DIM];
        R2[j] = dwq[j][2 * DIM];
        R3[j] = dwq[j][3 * DIM];
        dwq[j] += 4 * DIM;               // now points at step s+4
    }

    __syncthreads();   // one-time full sync (xt[0], dtp ready)

    // Raw barrier per step: drain LDS only (lgkmcnt), never vmcnt -> dW ring
    // loads stay in flight across barriers (T3/T4 pattern).
#define STEP(S, R, PF, XR, XW, KOFF)                                          \
    {                                                                         \
        const float2 dtc = dtp[S];                                            \
        FragU a0, a1;                                                         \
        a0.q = XR[ra0];                                                       \
        a1.q = XR[ra1];                                                       \
        f32x4 adr = {bdr, bdr, bdr, bdr};                                     \
        f32x4 adi = {bdi, bdi, bdi, bdi};                                     \
        adr = __builtin_amdgcn_mfma_f32_16x16x32_bf16(a0.v, bd0.v, adr, 0, 0, 0); \
        adr = __builtin_amdgcn_mfma_f32_16x16x32_bf16(a1.v, bd1.v, adr, 0, 0, 0); \
        adi = __builtin_amdgcn_mfma_f32_16x16x32_bf16(a0.v, bs0.v, adi, 0, 0, 0); \
        adi = __builtin_amdgcn_mfma_f32_16x16x32_bf16(a1.v, bs1.v, adi, 0, 0, 0); \
        _Pragma("unroll")                                                     \
        for (int j = 0; j < 4; ++j) {                                         \
            const float xn = fmaf(dtc.x, adr[j], xst[j])                      \
                             + adi[j] * (dtc.y * R[j]);                       \
            xst[j] = xn;                                                      \
            __builtin_nontemporal_store(xn, op[j] + (size_t)((S) + 1) * DIM); \
            XW[woff[j]] = (unsigned short)pk_bf16(xn, xn);                    \
        }                                                                     \
        if (PF) {                                                             \
            _Pragma("unroll")                                                 \
            for (int j = 0; j < 4; ++j) R[j] = dwq[j][(KOFF) * DIM];          \
        }                                                                     \
        asm volatile("s_waitcnt lgkmcnt(0)" ::: "memory");                    \
        __builtin_amdgcn_s_barrier();                                         \
        __builtin_amdgcn_sched_barrier(0);                                    \
    }

    // main loop: groups of 4 steps; group at s prefetches steps s+4..s+7
    for (int it = 0; it < NSTEPS / 4 - 1; ++it) {
        const int s = it * 4;
        STEP(s + 0, R0, 1, xr0, xw1, 0)
        STEP(s + 1, R1, 1, xr1, xw0, 1)
        STEP(s + 2, R2, 1, xr0, xw1, 2)
        STEP(s + 3, R3, 1, xr1, xw0, 3)
#pragma unroll
        for (int j = 0; j < 4; ++j) dwq[j] += 4 * DIM;
    }
    // epilogue: steps 496..499, no prefetch
    {
        const int s = NSTEPS - 4;
        STEP(s + 0, R0, 0, xr0, xw1, 0)
        STEP(s + 1, R1, 0, xr1, xw0, 1)
        STEP(s + 2, R2, 0, xr0, xw1, 2)
        STEP(s + 3, R3, 0, xr1, xw0, 3)
    }
#undef STEP
}

extern "C" void kernel_launch(void* const* d_in, const int* in_sizes, int n_in,
                              void* d_out, int out_size, void* d_ws, size_t ws_size,
                              hipStream_t stream) {
    const float* x0             = (const float*)d_in[0];
    const float* dW             = (const float*)d_in[1];
    const float* drift          = (const float*)d_in[2];
    const float* drift_bias     = (const float*)d_in[3];
    const float* diffusion      = (const float*)d_in[4];
    const float* diffusion_bias = (const float*)d_in[5];
    const float* ts             = (const float*)d_in[6];
    float* out = (float*)d_out;

    dim3 grid(NPATH / PPW);   // 128 blocks (one 16-path tile each)
    dim3 block(256);          // 4 waves
    hipLaunchKernelGGL(sde_mfma_mw_kernel, grid, block, 0, stream,
                       x0, dW, drift, drift_bias, diffusion, diffusion_bias,
                       ts, out);
}